// Round 5
// baseline (854.690 us; speedup 1.0000x reference)
//
#include <hip/hip_runtime.h>
#include <hip/hip_cooperative_groups.h>
#include <stdint.h>

namespace cg = cooperative_groups;

#define NBLK 1024

// Per-thread partial of w[0..n) . x[0..n), 256-thread block, float4 weights.
// Handles arbitrary 4B-granular row alignment (stride 2049 rows).
__device__ __forceinline__ float dot_row(const float* __restrict__ w,
                                         const float* __restrict__ x,
                                         int n, int tid)
{
    int mis = (int)(((uintptr_t)w >> 2) & 3);
    int start = (4 - mis) & 3;
    if (start > n) start = n;
    float sum = 0.0f;
    if (tid < start) sum += w[tid] * x[tid];
    int nv = (n - start) >> 2;
    const float4* wv = (const float4*)(w + start);
    const float* xs = x + start;
    for (int g = tid; g < nv; g += 256) {
        float4 u = wv[g];
        const float* xp = xs + 4 * g;
        sum += u.x * xp[0] + u.y * xp[1] + u.z * xp[2] + u.w * xp[3];
    }
    int t = start + nv * 4 + tid;
    if (t < n) sum += w[t] * x[t];
    return sum;
}

// GEMV stage: y = (relu?)(B + W.x), 2 rows per block-iteration (doubles loads
// in flight between reduction barriers). TSCOL=1: fused [x, ts] last column.
template<int RELU, int TSCOL>
__device__ void gemv_stage(const float* __restrict__ W, const float* __restrict__ B,
                           const float* __restrict__ x, const float* __restrict__ ts,
                           float* __restrict__ y, int rows, int cols,
                           float* __restrict__ red)
{
    int tid = threadIdx.x;
    int n = TSCOL ? cols - 1 : cols;
    for (int base = blockIdx.x * 2; base < rows; base += NBLK * 2) {
        int r1ok = (base + 1 < rows);
        const float* w0 = W + (size_t)base * (size_t)cols;
        const float* w1 = w0 + (r1ok ? cols : 0);
        float s0 = dot_row(w0, x, n, tid);
        float s1 = dot_row(w1, x, n, tid);
        if (TSCOL && tid == 0) {
            float t0 = ts[0];
            s0 += w0[n] * t0;
            s1 += w1[n] * t0;
        }
        #pragma unroll
        for (int off = 32; off > 0; off >>= 1) {
            s0 += __shfl_down(s0, off);
            s1 += __shfl_down(s1, off);
        }
        __syncthreads();   // red[] safe to overwrite (prev iteration consumed)
        if ((tid & 63) == 0) { red[tid >> 6] = s0; red[4 + (tid >> 6)] = s1; }
        __syncthreads();
        if (tid == 0) {
            float r = red[0] + red[1] + red[2] + red[3] + B[base];
            if (RELU) r = fmaxf(r, 0.0f);
            y[base] = r;
        } else if (tid == 64 && r1ok) {
            float r = red[4] + red[5] + red[6] + red[7] + B[base + 1];
            if (RELU) r = fmaxf(r, 0.0f);
            y[base + 1] = r;
        }
    }
}

// RK4-3/8 CPG ODE step, executed by block 0 only (256 threads, lanes 0-31
// active in compute phases). Numerics identical to the R3/R4 passing version.
// Reference quirks preserved:
//   dy = concat([a_dot, phase_dots, a_dd]) -> phase_dots integrates slot [n:2n]
//   cpg_out uses a = new_state[:n], "ph" = new_state[n:2n]
__device__ void ode_stage(const float* __restrict__ state, const float* __restrict__ ts,
                          const float* __restrict__ params, float* __restrict__ cpg,
                          float* __restrict__ out_state,
                          float* s_cw, float* s_spb, float* s_cpb,
                          float* s_s, float* s_c)
{
    const float CONV = 1000.0f;
    int tid = threadIdx.x;

    // coalesced staging; 1024 sincos spread over 256 threads (+1-pad rows)
    for (int k = tid; k < 1024; k += 256) {
        int p = k + (k >> 5);
        s_cw[p] = params[64 + k];
        float sp, cp;
        sincosf(params[1088 + k], &sp, &cp);
        s_spb[p] = sp;
        s_cpb[p] = cp;
    }
    __syncthreads();

    bool act = (tid < 32);
    int i = tid;
    float ia = 0.f, ifr = 0.f, y0a = 0.f, y0b = 0.f, y0c = 0.f;
    if (act) {
        ia  = params[i];
        ifr = params[32 + i];
        y0a = state[i];
        y0b = state[32 + i];
        y0c = state[64 + i];
    }
    float h = ts[0];

    float k1a=0,k1b=0,k1c=0, k2a=0,k2b=0,k2c=0, k3a=0,k3b=0,k3c=0, k4a=0,k4b=0,k4c=0;

    auto do_eval = [&](float a, float ad, float ph,
                       float& fa, float& fb, float& fc) {
        __syncthreads();
        if (act) {
            float s, c;
            sincosf(ph, &s, &c);
            s_s[i] = s; s_c[i] = c;
        }
        __syncthreads();
        if (act) {
            float si = s_s[i], ci = s_c[i];
            float ssum = 0.0f;
            #pragma unroll
            for (int j = 0; j < 32; j++) {
                float sj = s_s[j], cj = s_c[j];
                float sdp = sj * ci - cj * si;              // sin(ph_j - ph_i)
                float cdp = cj * ci + sj * si;              // cos(ph_j - ph_i)
                int p = i * 33 + j;
                float sv = sdp * s_cpb[p] - cdp * s_spb[p]; // sin(dphi - pb)
                ssum += s_cw[p] * sv;
            }
            fa = ad;
            fb = ifr + a * ssum;
            fc = CONV * (CONV * 0.25f * (ia - a) - ad);
        }
    };

    do_eval(y0a, y0b, y0c, k1a, k1b, k1c);
    do_eval(y0a + h * k1a / 3.0f,
            y0b + h * k1b / 3.0f,
            y0c + h * k1c / 3.0f, k2a, k2b, k2c);
    do_eval(y0a + h * (k2a - k1a / 3.0f),
            y0b + h * (k2b - k1b / 3.0f),
            y0c + h * (k2c - k1c / 3.0f), k3a, k3b, k3c);
    do_eval(y0a + h * (k1a - k2a + k3a),
            y0b + h * (k1b - k2b + k3b),
            y0c + h * (k1c - k2c + k3c), k4a, k4b, k4c);

    if (act) {
        float na = y0a + h * 0.125f * (k1a + 3.0f * (k2a + k3a) + k4a);
        float nb = y0b + h * 0.125f * (k1b + 3.0f * (k2b + k3b) + k4b);
        float nc = y0c + h * 0.125f * (k1c + 3.0f * (k2c + k3c) + k4c);
        out_state[i]      = na;
        out_state[32 + i] = nb;
        out_state[64 + i] = nc;
        cpg[i]      = na * cosf(nb);   // reference quirk: "ph" = new_state[32:64]
        cpg[32 + i] = na * sinf(nb);
    }
}

// Single cooperative kernel: 7 stages separated by grid.sync().
// 1024 blocks x 256 thr, launch_bounds(256,4) -> <=128 VGPR -> 4 blocks/CU
// guaranteed co-resident (1024 total), satisfying cooperative-launch capacity.
__global__ __launch_bounds__(256, 4) void fused_k(
    const float* state, const float* x, const float* ts,
    const float* inW0, const float* inb0,
    const float* inW1, const float* inb1,
    const float* inW2, const float* inb2,
    const float* oW0,  const float* ob0,
    const float* oW1,  const float* ob1,
    const float* oW2,  const float* ob2,
    float* out, float* ws)
{
    cg::grid_group grid = cg::this_grid();

    float* h0  = ws;            // 4096
    float* h1  = ws + 4096;     // 4096
    float* pr  = ws + 8192;     // 2112
    float* cpg = ws + 10304;    // 64
    float* g0  = ws + 10368;    // 2048
    float* g1  = ws + 12416;    // 2048

    __shared__ float s_red[8];
    __shared__ float s_cw[1056], s_spb[1056], s_cpb[1056];
    __shared__ float s_s[32], s_c[32];

    gemv_stage<1,1>(inW0, inb0, x,   ts, h0, 4096, 2049, s_red);
    grid.sync();
    gemv_stage<1,0>(inW1, inb1, h0,  nullptr, h1, 4096, 4096, s_red);
    grid.sync();
    gemv_stage<0,0>(inW2, inb2, h1,  nullptr, pr, 2112, 4096, s_red);
    grid.sync();
    if (blockIdx.x == 0)
        ode_stage(state, ts, pr, cpg, out, s_cw, s_spb, s_cpb, s_s, s_c);
    grid.sync();
    gemv_stage<1,0>(oW0, ob0, cpg, nullptr, g0, 2048, 64, s_red);
    grid.sync();
    gemv_stage<1,0>(oW1, ob1, g0,  nullptr, g1, 2048, 2048, s_red);
    grid.sync();
    gemv_stage<0,0>(oW2, ob2, g1,  nullptr, out + 96, 1024, 2048, s_red);
}

extern "C" void kernel_launch(void* const* d_in, const int* in_sizes, int n_in,
                              void* d_out, int out_size, void* d_ws, size_t ws_size,
                              hipStream_t stream) {
    const float* state = (const float*)d_in[0];   // 96
    const float* x     = (const float*)d_in[1];   // 2048
    const float* ts    = (const float*)d_in[2];   // 1
    const float* inW0  = (const float*)d_in[3];   // 4096 x 2049
    const float* inb0  = (const float*)d_in[4];   // 4096
    const float* inW1  = (const float*)d_in[5];   // 4096 x 4096
    const float* inb1  = (const float*)d_in[6];   // 4096
    const float* inW2  = (const float*)d_in[7];   // 2112 x 4096
    const float* inb2  = (const float*)d_in[8];   // 2112
    const float* oW0   = (const float*)d_in[9];   // 2048 x 64
    const float* ob0   = (const float*)d_in[10];  // 2048
    const float* oW1   = (const float*)d_in[11];  // 2048 x 2048
    const float* ob1   = (const float*)d_in[12];  // 2048
    const float* oW2   = (const float*)d_in[13];  // 1024 x 2048
    const float* ob2   = (const float*)d_in[14];  // 1024

    float* out = (float*)d_out;
    float* ws  = (float*)d_ws;

    void* kargs[] = {
        (void*)&state, (void*)&x, (void*)&ts,
        (void*)&inW0, (void*)&inb0,
        (void*)&inW1, (void*)&inb1,
        (void*)&inW2, (void*)&inb2,
        (void*)&oW0,  (void*)&ob0,
        (void*)&oW1,  (void*)&ob1,
        (void*)&oW2,  (void*)&ob2,
        (void*)&out,  (void*)&ws
    };
    hipLaunchCooperativeKernel((const void*)fused_k, dim3(NBLK), dim3(256),
                               kargs, 0, stream);
}

// Round 6
// 220.351 us; speedup vs baseline: 3.8788x; 3.8788x over previous
//
#include <hip/hip_runtime.h>
#include <stdint.h>

// ---------------------------------------------------------------------------
// Wave-per-row GEMV: y[row] = (relu?)(B[row] + W[row,:].x)
// 256-thread block = 4 independent waves = 4 rows. No LDS, no __syncthreads.
// 8-deep unrolled float4 weight stream -> up to 16 loads in flight per lane.
// TSCOL=1: last column multiplied by ts[0] (fuses the [x, t] concat).
// ---------------------------------------------------------------------------
template<int RELU, int TSCOL>
__global__ __launch_bounds__(256) void gemv_k(
    const float* __restrict__ W, const float* __restrict__ B,
    const float* __restrict__ x, const float* __restrict__ ts,
    float* __restrict__ y, int rows, int cols)
{
    int wv   = threadIdx.x >> 6;
    int lane = threadIdx.x & 63;
    int row  = blockIdx.x * 4 + wv;
    if (row >= rows) return;

    int n = TSCOL ? cols - 1 : cols;
    const float* w = W + (size_t)row * (size_t)cols;

    // scalar head to 16B alignment (odd stride 2049 rows land anywhere)
    int mis = (int)(((uintptr_t)w >> 2) & 3);
    int start = (4 - mis) & 3;
    if (start > n) start = n;

    float sum = 0.0f;
    if (lane < start) sum += w[lane] * x[lane];

    int nv = (n - start) >> 2;
    const float4* wp = (const float4*)(w + start);
    const float* xs = x + start;

    int g = lane;
    // 8-deep unroll: 8 independent float4 loads in flight per lane
    for (; g + 448 < nv; g += 512) {
        float4 u0 = wp[g];
        float4 u1 = wp[g + 64];
        float4 u2 = wp[g + 128];
        float4 u3 = wp[g + 192];
        float4 u4 = wp[g + 256];
        float4 u5 = wp[g + 320];
        float4 u6 = wp[g + 384];
        float4 u7 = wp[g + 448];
        const float* x0 = xs + 4 * g;
        sum += u0.x * x0[0]    + u0.y * x0[1]    + u0.z * x0[2]    + u0.w * x0[3];
        sum += u1.x * x0[256]  + u1.y * x0[257]  + u1.z * x0[258]  + u1.w * x0[259];
        sum += u2.x * x0[512]  + u2.y * x0[513]  + u2.z * x0[514]  + u2.w * x0[515];
        sum += u3.x * x0[768]  + u3.y * x0[769]  + u3.z * x0[770]  + u3.w * x0[771];
        sum += u4.x * x0[1024] + u4.y * x0[1025] + u4.z * x0[1026] + u4.w * x0[1027];
        sum += u5.x * x0[1280] + u5.y * x0[1281] + u5.z * x0[1282] + u5.w * x0[1283];
        sum += u6.x * x0[1536] + u6.y * x0[1537] + u6.z * x0[1538] + u6.w * x0[1539];
        sum += u7.x * x0[1792] + u7.y * x0[1793] + u7.z * x0[1794] + u7.w * x0[1795];
    }
    for (; g < nv; g += 64) {
        float4 u = wp[g];
        const float* xp = xs + 4 * g;
        sum += u.x * xp[0] + u.y * xp[1] + u.z * xp[2] + u.w * xp[3];
    }
    int t = start + nv * 4 + lane;
    if (t < n) sum += w[t] * x[t];
    if (TSCOL && lane == 0) sum += w[n] * ts[0];

    #pragma unroll
    for (int off = 32; off > 0; off >>= 1) sum += __shfl_down(sum, off);

    if (lane == 0) {
        float r = sum + B[row];
        if (RELU) r = fmaxf(r, 0.0f);
        y[row] = r;
    }
}

// ---------------------------------------------------------------------------
// RK4-3/8 CPG ODE step (identical numerics to the passing R4 version).
// Reference quirks preserved exactly:
//   dy = concat([a_dot, phase_dots, a_dd]) -> phase_dots integrates slot [n:2n]
//   cpg_out uses a = new_state[:n], "ph" = new_state[n:2n]
// ---------------------------------------------------------------------------
__global__ __launch_bounds__(64) void ode_k(
    const float* __restrict__ state, const float* __restrict__ ts,
    const float* __restrict__ params, float* __restrict__ cpg,
    float* __restrict__ out_state)
{
    const float CONV = 1000.0f;
    __shared__ float s_cw[32 * 33];   // +1 pad rows -> conflict-free row reads
    __shared__ float s_spb[32 * 33];
    __shared__ float s_cpb[32 * 33];
    __shared__ float s_s[32], s_c[32];
    int tid = threadIdx.x;

    for (int k = tid; k < 1024; k += 64) {
        int p = k + (k >> 5);
        s_cw[p] = params[64 + k];
        float sp, cp;
        sincosf(params[1088 + k], &sp, &cp);
        s_spb[p] = sp;
        s_cpb[p] = cp;
    }
    __syncthreads();

    bool act = (tid < 32);
    int i = tid;
    float ia = 0.f, ifr = 0.f, y0a = 0.f, y0b = 0.f, y0c = 0.f;
    if (act) {
        ia  = params[i];
        ifr = params[32 + i];
        y0a = state[i];
        y0b = state[32 + i];
        y0c = state[64 + i];
    }
    float h = ts[0];

    float k1a=0,k1b=0,k1c=0, k2a=0,k2b=0,k2c=0, k3a=0,k3b=0,k3c=0, k4a=0,k4b=0,k4c=0;

    auto do_eval = [&](float a, float ad, float ph,
                       float& fa, float& fb, float& fc) {
        __syncthreads();
        if (act) {
            float s, c;
            sincosf(ph, &s, &c);
            s_s[i] = s; s_c[i] = c;
        }
        __syncthreads();
        if (act) {
            float si = s_s[i], ci = s_c[i];
            float ssum = 0.0f;
            #pragma unroll
            for (int j = 0; j < 32; j++) {
                float sj = s_s[j], cj = s_c[j];
                float sdp = sj * ci - cj * si;              // sin(ph_j - ph_i)
                float cdp = cj * ci + sj * si;              // cos(ph_j - ph_i)
                int p = i * 33 + j;
                float sv = sdp * s_cpb[p] - cdp * s_spb[p]; // sin(dphi - pb)
                ssum += s_cw[p] * sv;
            }
            fa = ad;
            fb = ifr + a * ssum;
            fc = CONV * (CONV * 0.25f * (ia - a) - ad);
        }
    };

    do_eval(y0a, y0b, y0c, k1a, k1b, k1c);
    do_eval(y0a + h * k1a / 3.0f,
            y0b + h * k1b / 3.0f,
            y0c + h * k1c / 3.0f, k2a, k2b, k2c);
    do_eval(y0a + h * (k2a - k1a / 3.0f),
            y0b + h * (k2b - k1b / 3.0f),
            y0c + h * (k2c - k1c / 3.0f), k3a, k3b, k3c);
    do_eval(y0a + h * (k1a - k2a + k3a),
            y0b + h * (k1b - k2b + k3b),
            y0c + h * (k1c - k2c + k3c), k4a, k4b, k4c);

    if (act) {
        float na = y0a + h * 0.125f * (k1a + 3.0f * (k2a + k3a) + k4a);
        float nb = y0b + h * 0.125f * (k1b + 3.0f * (k2b + k3b) + k4b);
        float nc = y0c + h * 0.125f * (k1c + 3.0f * (k2c + k3c) + k4c);
        out_state[i]      = na;
        out_state[32 + i] = nb;
        out_state[64 + i] = nc;
        cpg[i]      = na * cosf(nb);   // reference quirk: "ph" = new_state[32:64]
        cpg[32 + i] = na * sinf(nb);
    }
}

extern "C" void kernel_launch(void* const* d_in, const int* in_sizes, int n_in,
                              void* d_out, int out_size, void* d_ws, size_t ws_size,
                              hipStream_t stream) {
    const float* state = (const float*)d_in[0];   // 96
    const float* x     = (const float*)d_in[1];   // 2048
    const float* ts    = (const float*)d_in[2];   // 1
    const float* inW0  = (const float*)d_in[3];   // 4096 x 2049
    const float* inb0  = (const float*)d_in[4];   // 4096
    const float* inW1  = (const float*)d_in[5];   // 4096 x 4096
    const float* inb1  = (const float*)d_in[6];   // 4096
    const float* inW2  = (const float*)d_in[7];   // 2112 x 4096
    const float* inb2  = (const float*)d_in[8];   // 2112
    const float* oW0   = (const float*)d_in[9];   // 2048 x 64
    const float* ob0   = (const float*)d_in[10];  // 2048
    const float* oW1   = (const float*)d_in[11];  // 2048 x 2048
    const float* ob1   = (const float*)d_in[12];  // 2048
    const float* oW2   = (const float*)d_in[13];  // 1024 x 2048
    const float* ob2   = (const float*)d_in[14];  // 1024

    float* ws  = (float*)d_ws;
    float* h0  = ws;            // 4096
    float* h1  = ws + 4096;     // 4096
    float* pr  = ws + 8192;     // 2112
    float* cpg = ws + 10304;    // 64
    float* g0  = ws + 10368;    // 2048
    float* g1  = ws + 12416;    // 2048

    float* out = (float*)d_out; // 96 (new_state) + 1024, fp32

    gemv_k<1,1><<<1024, 256, 0, stream>>>(inW0, inb0, x,   ts,      h0, 4096, 2049);
    gemv_k<1,0><<<1024, 256, 0, stream>>>(inW1, inb1, h0,  nullptr, h1, 4096, 4096);
    gemv_k<0,0><<< 528, 256, 0, stream>>>(inW2, inb2, h1,  nullptr, pr, 2112, 4096);
    ode_k<<<1, 64, 0, stream>>>(state, ts, pr, cpg, out);
    gemv_k<1,0><<< 512, 256, 0, stream>>>(oW0,  ob0,  cpg, nullptr, g0, 2048, 64);
    gemv_k<1,0><<< 512, 256, 0, stream>>>(oW1,  ob1,  g0,  nullptr, g1, 2048, 2048);
    gemv_k<0,0><<< 256, 256, 0, stream>>>(oW2,  ob2,  g1,  nullptr, out + 96, 1024, 2048);
}

// Round 7
// 217.380 us; speedup vs baseline: 3.9318x; 1.0137x over previous
//
#include <hip/hip_runtime.h>
#include <stdint.h>

// ---------------------------------------------------------------------------
// Wave-per-row GEMV: y[row] = (relu?)(B[row] + W[row,:].x)
// 256-thread block = 4 waves = 4 rows. No LDS, no barriers.
// XVEC=1 (stride%4==0 layers): x loaded as float4 -> 2 VMEM instr / 16B of W.
// XVEC=0 (odd stride 2049): scalar head to 16B + scalar x loads.
// TSCOL=1: last column multiplied by ts[0] (fuses the [x, t] concat).
// ---------------------------------------------------------------------------
template<int RELU, int TSCOL, int XVEC>
__global__ __launch_bounds__(256) void gemv_k(
    const float* __restrict__ W, const float* __restrict__ B,
    const float* __restrict__ x, const float* __restrict__ ts,
    float* __restrict__ y, int rows, int cols)
{
    int wv   = threadIdx.x >> 6;
    int lane = threadIdx.x & 63;
    int row  = blockIdx.x * 4 + wv;
    if (row >= rows) return;

    int n = TSCOL ? cols - 1 : cols;
    const float* w = W + (size_t)row * (size_t)cols;
    float sum = 0.0f;

    if (XVEC) {
        // rows 16B-aligned by construction (stride % 4 == 0, base 256B-aligned)
        int nv = n >> 2;
        const float4* wp = (const float4*)w;
        const float4* xp = (const float4*)x;
        int g = lane;
        for (; g + 448 < nv; g += 512) {
            float4 u0 = wp[g];       float4 v0 = xp[g];
            float4 u1 = wp[g + 64];  float4 v1 = xp[g + 64];
            float4 u2 = wp[g + 128]; float4 v2 = xp[g + 128];
            float4 u3 = wp[g + 192]; float4 v3 = xp[g + 192];
            float4 u4 = wp[g + 256]; float4 v4 = xp[g + 256];
            float4 u5 = wp[g + 320]; float4 v5 = xp[g + 320];
            float4 u6 = wp[g + 384]; float4 v6 = xp[g + 384];
            float4 u7 = wp[g + 448]; float4 v7 = xp[g + 448];
            sum += u0.x*v0.x + u0.y*v0.y + u0.z*v0.z + u0.w*v0.w;
            sum += u1.x*v1.x + u1.y*v1.y + u1.z*v1.z + u1.w*v1.w;
            sum += u2.x*v2.x + u2.y*v2.y + u2.z*v2.z + u2.w*v2.w;
            sum += u3.x*v3.x + u3.y*v3.y + u3.z*v3.z + u3.w*v3.w;
            sum += u4.x*v4.x + u4.y*v4.y + u4.z*v4.z + u4.w*v4.w;
            sum += u5.x*v5.x + u5.y*v5.y + u5.z*v5.z + u5.w*v5.w;
            sum += u6.x*v6.x + u6.y*v6.y + u6.z*v6.z + u6.w*v6.w;
            sum += u7.x*v7.x + u7.y*v7.y + u7.z*v7.z + u7.w*v7.w;
        }
        for (; g < nv; g += 64) {
            float4 u = wp[g];
            float4 v = xp[g];
            sum += u.x*v.x + u.y*v.y + u.z*v.z + u.w*v.w;
        }
        int t = nv * 4 + lane;
        if (t < n) sum += w[t] * x[t];
    } else {
        int mis = (int)(((uintptr_t)w >> 2) & 3);
        int start = (4 - mis) & 3;
        if (start > n) start = n;
        if (lane < start) sum += w[lane] * x[lane];
        int nv = (n - start) >> 2;
        const float4* wp = (const float4*)(w + start);
        const float* xs = x + start;
        int g = lane;
        for (; g + 448 < nv; g += 512) {
            float4 u0 = wp[g];
            float4 u1 = wp[g + 64];
            float4 u2 = wp[g + 128];
            float4 u3 = wp[g + 192];
            float4 u4 = wp[g + 256];
            float4 u5 = wp[g + 320];
            float4 u6 = wp[g + 384];
            float4 u7 = wp[g + 448];
            const float* x0 = xs + 4 * g;
            sum += u0.x * x0[0]    + u0.y * x0[1]    + u0.z * x0[2]    + u0.w * x0[3];
            sum += u1.x * x0[256]  + u1.y * x0[257]  + u1.z * x0[258]  + u1.w * x0[259];
            sum += u2.x * x0[512]  + u2.y * x0[513]  + u2.z * x0[514]  + u2.w * x0[515];
            sum += u3.x * x0[768]  + u3.y * x0[769]  + u3.z * x0[770]  + u3.w * x0[771];
            sum += u4.x * x0[1024] + u4.y * x0[1025] + u4.z * x0[1026] + u4.w * x0[1027];
            sum += u5.x * x0[1280] + u5.y * x0[1281] + u5.z * x0[1282] + u5.w * x0[1283];
            sum += u6.x * x0[1536] + u6.y * x0[1537] + u6.z * x0[1538] + u6.w * x0[1539];
            sum += u7.x * x0[1792] + u7.y * x0[1793] + u7.z * x0[1794] + u7.w * x0[1795];
        }
        for (; g < nv; g += 64) {
            float4 u = wp[g];
            const float* xp = xs + 4 * g;
            sum += u.x * xp[0] + u.y * xp[1] + u.z * xp[2] + u.w * xp[3];
        }
        int t = start + nv * 4 + lane;
        if (t < n) sum += w[t] * x[t];
    }
    if (TSCOL && lane == 0) sum += w[n] * ts[0];

    #pragma unroll
    for (int off = 32; off > 0; off >>= 1) sum += __shfl_down(sum, off);

    if (lane == 0) {
        float r = sum + B[row];
        if (RELU) r = fmaxf(r, 0.0f);
        y[row] = r;
    }
}

// ---------------------------------------------------------------------------
// Fused ODE + oW0. 512 blocks x 256 threads. EVERY block redundantly computes
// the RK4-3/8 step from pr (deterministic fp32 -> identical results in all
// blocks; removes the solo-block ode launch + its gap). Block 0 writes
// out_state; all blocks then compute 4 rows of g0 = relu(ob0 + oW0 . cpg)
// from LDS-held cpg (64 cols, one product per lane, shuffle reduce).
// Numerics identical to the R4/R6 passing ode kernel. Reference quirks:
//   dy = concat([a_dot, phase_dots, a_dd]) -> phase_dots integrates slot [n:2n]
//   cpg_out uses a = new_state[:n], "ph" = new_state[n:2n]
// ---------------------------------------------------------------------------
__global__ __launch_bounds__(256) void ode_ow0_k(
    const float* __restrict__ state, const float* __restrict__ ts,
    const float* __restrict__ params,
    const float* __restrict__ oW0, const float* __restrict__ ob0,
    float* __restrict__ g0, float* __restrict__ out_state)
{
    const float CONV = 1000.0f;
    __shared__ float s_cw[32 * 33];   // +1 pad rows -> conflict-free row reads
    __shared__ float s_spb[32 * 33];
    __shared__ float s_cpb[32 * 33];
    __shared__ float s_s[32], s_c[32];
    __shared__ float s_cpg[64];
    int tid = threadIdx.x;

    for (int k = tid; k < 1024; k += 256) {
        int p = k + (k >> 5);
        s_cw[p] = params[64 + k];
        float sp, cp;
        sincosf(params[1088 + k], &sp, &cp);
        s_spb[p] = sp;
        s_cpb[p] = cp;
    }
    __syncthreads();

    bool act = (tid < 32);
    int i = tid;
    float ia = 0.f, ifr = 0.f, y0a = 0.f, y0b = 0.f, y0c = 0.f;
    if (act) {
        ia  = params[i];
        ifr = params[32 + i];
        y0a = state[i];
        y0b = state[32 + i];
        y0c = state[64 + i];
    }
    float h = ts[0];

    float k1a=0,k1b=0,k1c=0, k2a=0,k2b=0,k2c=0, k3a=0,k3b=0,k3c=0, k4a=0,k4b=0,k4c=0;

    auto do_eval = [&](float a, float ad, float ph,
                       float& fa, float& fb, float& fc) {
        __syncthreads();
        if (act) {
            float s, c;
            sincosf(ph, &s, &c);
            s_s[i] = s; s_c[i] = c;
        }
        __syncthreads();
        if (act) {
            float si = s_s[i], ci = s_c[i];
            float ssum = 0.0f;
            #pragma unroll
            for (int j = 0; j < 32; j++) {
                float sj = s_s[j], cj = s_c[j];
                float sdp = sj * ci - cj * si;              // sin(ph_j - ph_i)
                float cdp = cj * ci + sj * si;              // cos(ph_j - ph_i)
                int p = i * 33 + j;
                float sv = sdp * s_cpb[p] - cdp * s_spb[p]; // sin(dphi - pb)
                ssum += s_cw[p] * sv;
            }
            fa = ad;
            fb = ifr + a * ssum;
            fc = CONV * (CONV * 0.25f * (ia - a) - ad);
        }
    };

    do_eval(y0a, y0b, y0c, k1a, k1b, k1c);
    do_eval(y0a + h * k1a / 3.0f,
            y0b + h * k1b / 3.0f,
            y0c + h * k1c / 3.0f, k2a, k2b, k2c);
    do_eval(y0a + h * (k2a - k1a / 3.0f),
            y0b + h * (k2b - k1b / 3.0f),
            y0c + h * (k2c - k1c / 3.0f), k3a, k3b, k3c);
    do_eval(y0a + h * (k1a - k2a + k3a),
            y0b + h * (k1b - k2b + k3b),
            y0c + h * (k1c - k2c + k3c), k4a, k4b, k4c);

    if (act) {
        float na = y0a + h * 0.125f * (k1a + 3.0f * (k2a + k3a) + k4a);
        float nb = y0b + h * 0.125f * (k1b + 3.0f * (k2b + k3b) + k4b);
        float nc = y0c + h * 0.125f * (k1c + 3.0f * (k2c + k3c) + k4c);
        if (blockIdx.x == 0) {
            out_state[i]      = na;
            out_state[32 + i] = nb;
            out_state[64 + i] = nc;
        }
        s_cpg[i]      = na * cosf(nb);  // reference quirk: "ph" = new_state[32:64]
        s_cpg[32 + i] = na * sinf(nb);
    }
    __syncthreads();

    // oW0 stage: 4 rows per block (one per wave), 64 cols from s_cpg
    int wv   = tid >> 6;
    int lane = tid & 63;
    int row  = blockIdx.x * 4 + wv;     // 512 blocks * 4 = 2048 rows
    float sum = oW0[(size_t)row * 64 + lane] * s_cpg[lane];
    #pragma unroll
    for (int off = 32; off > 0; off >>= 1) sum += __shfl_down(sum, off);
    if (lane == 0) g0[row] = fmaxf(sum + ob0[row], 0.0f);
}

extern "C" void kernel_launch(void* const* d_in, const int* in_sizes, int n_in,
                              void* d_out, int out_size, void* d_ws, size_t ws_size,
                              hipStream_t stream) {
    const float* state = (const float*)d_in[0];   // 96
    const float* x     = (const float*)d_in[1];   // 2048
    const float* ts    = (const float*)d_in[2];   // 1
    const float* inW0  = (const float*)d_in[3];   // 4096 x 2049
    const float* inb0  = (const float*)d_in[4];   // 4096
    const float* inW1  = (const float*)d_in[5];   // 4096 x 4096
    const float* inb1  = (const float*)d_in[6];   // 4096
    const float* inW2  = (const float*)d_in[7];   // 2112 x 4096
    const float* inb2  = (const float*)d_in[8];   // 2112
    const float* oW0   = (const float*)d_in[9];   // 2048 x 64
    const float* ob0   = (const float*)d_in[10];  // 2048
    const float* oW1   = (const float*)d_in[11];  // 2048 x 2048
    const float* ob1   = (const float*)d_in[12];  // 2048
    const float* oW2   = (const float*)d_in[13];  // 1024 x 2048
    const float* ob2   = (const float*)d_in[14];  // 1024

    float* ws  = (float*)d_ws;
    float* h0  = ws;            // 4096
    float* h1  = ws + 4096;     // 4096
    float* pr  = ws + 8192;     // 2112
    float* g0  = ws + 10368;    // 2048
    float* g1  = ws + 12416;    // 2048

    float* out = (float*)d_out; // 96 (new_state) + 1024, fp32

    gemv_k<1,1,0><<<1024, 256, 0, stream>>>(inW0, inb0, x,   ts,      h0, 4096, 2049);
    gemv_k<1,0,1><<<1024, 256, 0, stream>>>(inW1, inb1, h0,  nullptr, h1, 4096, 4096);
    gemv_k<0,0,1><<< 528, 256, 0, stream>>>(inW2, inb2, h1,  nullptr, pr, 2112, 4096);
    ode_ow0_k<<<512, 256, 0, stream>>>(state, ts, pr, oW0, ob0, g0, out);
    gemv_k<1,0,1><<< 512, 256, 0, stream>>>(oW1,  ob1,  g0,  nullptr, g1, 2048, 2048);
    gemv_k<0,0,1><<< 256, 256, 0, stream>>>(oW2,  ob2,  g1,  nullptr, out + 96, 1024, 2048);
}

// Round 8
// 213.778 us; speedup vs baseline: 3.9980x; 1.0169x over previous
//
#include <hip/hip_runtime.h>
#include <stdint.h>

// ---------------------------------------------------------------------------
// Wave-per-row GEMV (odd-stride path, used for inW0 stride 2049).
// 256-thread block = 4 waves = 4 rows. Scalar head to 16B, scalar x loads.
// TSCOL=1: last column multiplied by ts[0] (fuses the [x, t] concat).
// ---------------------------------------------------------------------------
template<int RELU, int TSCOL>
__global__ __launch_bounds__(256) void gemv_k(
    const float* __restrict__ W, const float* __restrict__ B,
    const float* __restrict__ x, const float* __restrict__ ts,
    float* __restrict__ y, int rows, int cols)
{
    int wv   = threadIdx.x >> 6;
    int lane = threadIdx.x & 63;
    int row  = blockIdx.x * 4 + wv;
    if (row >= rows) return;

    int n = TSCOL ? cols - 1 : cols;
    const float* w = W + (size_t)row * (size_t)cols;
    float sum = 0.0f;

    int mis = (int)(((uintptr_t)w >> 2) & 3);
    int start = (4 - mis) & 3;
    if (start > n) start = n;
    if (lane < start) sum += w[lane] * x[lane];
    int nv = (n - start) >> 2;
    const float4* wp = (const float4*)(w + start);
    const float* xs = x + start;
    int g = lane;
    for (; g + 448 < nv; g += 512) {
        float4 u0 = wp[g];
        float4 u1 = wp[g + 64];
        float4 u2 = wp[g + 128];
        float4 u3 = wp[g + 192];
        float4 u4 = wp[g + 256];
        float4 u5 = wp[g + 320];
        float4 u6 = wp[g + 384];
        float4 u7 = wp[g + 448];
        const float* x0 = xs + 4 * g;
        sum += u0.x * x0[0]    + u0.y * x0[1]    + u0.z * x0[2]    + u0.w * x0[3];
        sum += u1.x * x0[256]  + u1.y * x0[257]  + u1.z * x0[258]  + u1.w * x0[259];
        sum += u2.x * x0[512]  + u2.y * x0[513]  + u2.z * x0[514]  + u2.w * x0[515];
        sum += u3.x * x0[768]  + u3.y * x0[769]  + u3.z * x0[770]  + u3.w * x0[771];
        sum += u4.x * x0[1024] + u4.y * x0[1025] + u4.z * x0[1026] + u4.w * x0[1027];
        sum += u5.x * x0[1280] + u5.y * x0[1281] + u5.z * x0[1282] + u5.w * x0[1283];
        sum += u6.x * x0[1536] + u6.y * x0[1537] + u6.z * x0[1538] + u6.w * x0[1539];
        sum += u7.x * x0[1792] + u7.y * x0[1793] + u7.z * x0[1794] + u7.w * x0[1795];
    }
    for (; g < nv; g += 64) {
        float4 u = wp[g];
        const float* xp = xs + 4 * g;
        sum += u.x * xp[0] + u.y * xp[1] + u.z * xp[2] + u.w * xp[3];
    }
    int t = start + nv * 4 + lane;
    if (t < n) sum += w[t] * x[t];
    if (TSCOL && lane == 0) sum += w[n] * ts[0];

    #pragma unroll
    for (int off = 32; off > 0; off >>= 1) sum += __shfl_down(sum, off);

    if (lane == 0) {
        float r = sum + B[row];
        if (RELU) r = fmaxf(r, 0.0f);
        y[row] = r;
    }
}

// ---------------------------------------------------------------------------
// 2-rows-per-wave GEMV for 16B-aligned-stride layers (cols % 4 == 0).
// Each wave streams TWO adjacent W rows sharing one float4 x load:
// 3 VMEM instructions per 16B-of-row-pair (vs 4 for row-per-wave), 12 loads
// in flight per lane. 4 waves/block -> 8 rows/block.
// ---------------------------------------------------------------------------
template<int RELU>
__global__ __launch_bounds__(256) void gemv2_k(
    const float* __restrict__ W, const float* __restrict__ B,
    const float* __restrict__ x, float* __restrict__ y, int cols)
{
    int gw   = blockIdx.x * 4 + (threadIdx.x >> 6);
    int lane = threadIdx.x & 63;
    int r0 = gw * 2;

    const float4* w0p = (const float4*)(W + (size_t)r0 * (size_t)cols);
    const float4* w1p = (const float4*)(W + (size_t)(r0 + 1) * (size_t)cols);
    const float4* xp  = (const float4*)x;
    int nv = cols >> 2;

    float s0 = 0.0f, s1 = 0.0f;
    int g = lane;
    for (; g + 192 < nv; g += 256) {
        float4 xv0 = xp[g];       float4 a0 = w0p[g];       float4 b0 = w1p[g];
        float4 xv1 = xp[g + 64];  float4 a1 = w0p[g + 64];  float4 b1 = w1p[g + 64];
        float4 xv2 = xp[g + 128]; float4 a2 = w0p[g + 128]; float4 b2 = w1p[g + 128];
        float4 xv3 = xp[g + 192]; float4 a3 = w0p[g + 192]; float4 b3 = w1p[g + 192];
        s0 += a0.x*xv0.x + a0.y*xv0.y + a0.z*xv0.z + a0.w*xv0.w;
        s1 += b0.x*xv0.x + b0.y*xv0.y + b0.z*xv0.z + b0.w*xv0.w;
        s0 += a1.x*xv1.x + a1.y*xv1.y + a1.z*xv1.z + a1.w*xv1.w;
        s1 += b1.x*xv1.x + b1.y*xv1.y + b1.z*xv1.z + b1.w*xv1.w;
        s0 += a2.x*xv2.x + a2.y*xv2.y + a2.z*xv2.z + a2.w*xv2.w;
        s1 += b2.x*xv2.x + b2.y*xv2.y + b2.z*xv2.z + b2.w*xv2.w;
        s0 += a3.x*xv3.x + a3.y*xv3.y + a3.z*xv3.z + a3.w*xv3.w;
        s1 += b3.x*xv3.x + b3.y*xv3.y + b3.z*xv3.z + b3.w*xv3.w;
    }
    for (; g < nv; g += 64) {
        float4 xv = xp[g];
        float4 a = w0p[g];
        float4 b = w1p[g];
        s0 += a.x*xv.x + a.y*xv.y + a.z*xv.z + a.w*xv.w;
        s1 += b.x*xv.x + b.y*xv.y + b.z*xv.z + b.w*xv.w;
    }

    #pragma unroll
    for (int off = 32; off > 0; off >>= 1) {
        s0 += __shfl_down(s0, off);
        s1 += __shfl_down(s1, off);
    }
    if (lane == 0) {
        float v0 = s0 + B[r0];
        float v1 = s1 + B[r0 + 1];
        if (RELU) { v0 = fmaxf(v0, 0.0f); v1 = fmaxf(v1, 0.0f); }
        y[r0]     = v0;
        y[r0 + 1] = v1;
    }
}

// ---------------------------------------------------------------------------
// Fused ODE + oW0 (identical numerics to the passing R7 version).
// Every block redundantly computes the RK4-3/8 step (deterministic fp32 ->
// identical in all blocks); block 0 writes out_state; each block then does
// 4 rows of g0 = relu(ob0 + oW0 . cpg) from LDS-held cpg.
// Reference quirks preserved:
//   dy = concat([a_dot, phase_dots, a_dd]) -> phase_dots integrates slot [n:2n]
//   cpg_out uses a = new_state[:n], "ph" = new_state[n:2n]
// ---------------------------------------------------------------------------
__global__ __launch_bounds__(256) void ode_ow0_k(
    const float* __restrict__ state, const float* __restrict__ ts,
    const float* __restrict__ params,
    const float* __restrict__ oW0, const float* __restrict__ ob0,
    float* __restrict__ g0, float* __restrict__ out_state)
{
    const float CONV = 1000.0f;
    __shared__ float s_cw[32 * 33];
    __shared__ float s_spb[32 * 33];
    __shared__ float s_cpb[32 * 33];
    __shared__ float s_s[32], s_c[32];
    __shared__ float s_cpg[64];
    int tid = threadIdx.x;

    for (int k = tid; k < 1024; k += 256) {
        int p = k + (k >> 5);
        s_cw[p] = params[64 + k];
        float sp, cp;
        sincosf(params[1088 + k], &sp, &cp);
        s_spb[p] = sp;
        s_cpb[p] = cp;
    }
    __syncthreads();

    bool act = (tid < 32);
    int i = tid;
    float ia = 0.f, ifr = 0.f, y0a = 0.f, y0b = 0.f, y0c = 0.f;
    if (act) {
        ia  = params[i];
        ifr = params[32 + i];
        y0a = state[i];
        y0b = state[32 + i];
        y0c = state[64 + i];
    }
    float h = ts[0];

    float k1a=0,k1b=0,k1c=0, k2a=0,k2b=0,k2c=0, k3a=0,k3b=0,k3c=0, k4a=0,k4b=0,k4c=0;

    auto do_eval = [&](float a, float ad, float ph,
                       float& fa, float& fb, float& fc) {
        __syncthreads();
        if (act) {
            float s, c;
            sincosf(ph, &s, &c);
            s_s[i] = s; s_c[i] = c;
        }
        __syncthreads();
        if (act) {
            float si = s_s[i], ci = s_c[i];
            float ssum = 0.0f;
            #pragma unroll
            for (int j = 0; j < 32; j++) {
                float sj = s_s[j], cj = s_c[j];
                float sdp = sj * ci - cj * si;              // sin(ph_j - ph_i)
                float cdp = cj * ci + sj * si;              // cos(ph_j - ph_i)
                int p = i * 33 + j;
                float sv = sdp * s_cpb[p] - cdp * s_spb[p]; // sin(dphi - pb)
                ssum += s_cw[p] * sv;
            }
            fa = ad;
            fb = ifr + a * ssum;
            fc = CONV * (CONV * 0.25f * (ia - a) - ad);
        }
    };

    do_eval(y0a, y0b, y0c, k1a, k1b, k1c);
    do_eval(y0a + h * k1a / 3.0f,
            y0b + h * k1b / 3.0f,
            y0c + h * k1c / 3.0f, k2a, k2b, k2c);
    do_eval(y0a + h * (k2a - k1a / 3.0f),
            y0b + h * (k2b - k1b / 3.0f),
            y0c + h * (k2c - k1c / 3.0f), k3a, k3b, k3c);
    do_eval(y0a + h * (k1a - k2a + k3a),
            y0b + h * (k1b - k2b + k3b),
            y0c + h * (k1c - k2c + k3c), k4a, k4b, k4c);

    if (act) {
        float na = y0a + h * 0.125f * (k1a + 3.0f * (k2a + k3a) + k4a);
        float nb = y0b + h * 0.125f * (k1b + 3.0f * (k2b + k3b) + k4b);
        float nc = y0c + h * 0.125f * (k1c + 3.0f * (k2c + k3c) + k4c);
        if (blockIdx.x == 0) {
            out_state[i]      = na;
            out_state[32 + i] = nb;
            out_state[64 + i] = nc;
        }
        s_cpg[i]      = na * cosf(nb);  // reference quirk: "ph" = new_state[32:64]
        s_cpg[32 + i] = na * sinf(nb);
    }
    __syncthreads();

    int wv   = tid >> 6;
    int lane = tid & 63;
    int row  = blockIdx.x * 4 + wv;     // 512 blocks * 4 = 2048 rows
    float sum = oW0[(size_t)row * 64 + lane] * s_cpg[lane];
    #pragma unroll
    for (int off = 32; off > 0; off >>= 1) sum += __shfl_down(sum, off);
    if (lane == 0) g0[row] = fmaxf(sum + ob0[row], 0.0f);
}

extern "C" void kernel_launch(void* const* d_in, const int* in_sizes, int n_in,
                              void* d_out, int out_size, void* d_ws, size_t ws_size,
                              hipStream_t stream) {
    const float* state = (const float*)d_in[0];   // 96
    const float* x     = (const float*)d_in[1];   // 2048
    const float* ts    = (const float*)d_in[2];   // 1
    const float* inW0  = (const float*)d_in[3];   // 4096 x 2049
    const float* inb0  = (const float*)d_in[4];   // 4096
    const float* inW1  = (const float*)d_in[5];   // 4096 x 4096
    const float* inb1  = (const float*)d_in[6];   // 4096
    const float* inW2  = (const float*)d_in[7];   // 2112 x 4096
    const float* inb2  = (const float*)d_in[8];   // 2112
    const float* oW0   = (const float*)d_in[9];   // 2048 x 64
    const float* ob0   = (const float*)d_in[10];  // 2048
    const float* oW1   = (const float*)d_in[11];  // 2048 x 2048
    const float* ob1   = (const float*)d_in[12];  // 2048
    const float* oW2   = (const float*)d_in[13];  // 1024 x 2048
    const float* ob2   = (const float*)d_in[14];  // 1024

    float* ws  = (float*)d_ws;
    float* h0  = ws;            // 4096
    float* h1  = ws + 4096;     // 4096
    float* pr  = ws + 8192;     // 2112
    float* g0  = ws + 10368;    // 2048
    float* g1  = ws + 12416;    // 2048

    float* out = (float*)d_out; // 96 (new_state) + 1024, fp32

    gemv_k<1,1><<<1024, 256, 0, stream>>>(inW0, inb0, x, ts, h0, 4096, 2049);
    gemv2_k<1><<<512, 256, 0, stream>>>(inW1, inb1, h0, h1, 4096);   // 4096 rows
    gemv2_k<0><<<264, 256, 0, stream>>>(inW2, inb2, h1, pr, 4096);   // 2112 rows
    ode_ow0_k<<<512, 256, 0, stream>>>(state, ts, pr, oW0, ob0, g0, out);
    gemv2_k<1><<<256, 256, 0, stream>>>(oW1, ob1, g0, g1, 2048);     // 2048 rows
    gemv2_k<0><<<128, 256, 0, stream>>>(oW2, ob2, g1, out + 96, 2048); // 1024 rows
}